// Round 11
// baseline (76.339 us; speedup 1.0000x reference)
//
#include <hip/hip_runtime.h>
#include <hip/hip_cooperative_groups.h>

namespace cg = cooperative_groups;

// LengthRegulator: out[b,c,t] = x[b,c,owner(b,t)]; owner is the unique token
// whose segment covers frame t (path = 0/1 disjoint segment mask tiling
// [0,T_OUT) -> bmm(x,path) == gather; exact). owner(b,t) monotone in t.
//
// Cooperative single kernel (512 blocks x 512 threads, co-resident):
//   Phase 1 (banded idx build, == R10 K1): block g -> (b = g>>4, tile k=g&15),
//     TT=128. Anchor scans at t0,t0+128 give [o_lo,o_hi]; band scan (~17 rows)
//     finds the one-hot per t; race-free conditional LDS store; idx -> d_ws.
//   grid.sync()  -- replaces the inter-kernel drain + relaunch (the ~8us gap:
//     K2 previously couldn't start until K1's latency-bound tail retired).
//   Phase 2 (fat gather, == R10 K2 at CCHUNK=16): block g -> (b, c0=(g&15)*16).
//     16 x-rows staged in LDS (16 KiB), idx loaded once (1 int4/thread,
//     covers all 2048 t), 16 channels x {4 LDS gathers + 1 KiB/wave store}.
// Fallback: R10's two-kernel path if cooperative launch is unavailable.

#define LR_B 32
#define LR_C 256
#define LR_TIN 256
#define LR_TOUT 2048

#define SCAN_TT 128
#define CCHUNK 16

__global__ __launch_bounds__(512) void lr_coop(const float* __restrict__ x,
                                               const float* __restrict__ path,
                                               int* __restrict__ idx,
                                               float* __restrict__ out) {
    __shared__ float xs[CCHUNK][LR_TIN];       // 16 KiB; phase-1 aliases owner[]
    __shared__ int o_lo_s, o_hi_s;
    int* owner = reinterpret_cast<int*>(&xs[0][0]);   // 128 ints

    const int tid = threadIdx.x;
    const int g = blockIdx.x;
    const int b = g >> 4;
    const int k = g & 15;

    // ================= phase 1: banded idx build =================
    {
        const int t0 = k * SCAN_TT;
        const float* pb = path + (size_t)b * LR_TIN * LR_TOUT;

        if (tid < LR_TIN) {
            if (pb[(size_t)tid * LR_TOUT + t0] != 0.0f) o_lo_s = tid;
            if (t0 + SCAN_TT < LR_TOUT) {
                if (pb[(size_t)tid * LR_TOUT + t0 + SCAN_TT] != 0.0f) o_hi_s = tid;
            } else if (tid == 0) {
                o_hi_s = LR_TIN - 1;
            }
        }
        __syncthreads();
        const int o_lo = o_lo_s;
        const int o_hi = o_hi_s;

        // band scan: 16 rows x 32 float4-cols per pass
        const int col4 = tid & 31;
        const int row_off = tid >> 5;          // 0..15
        for (int r = o_lo + row_off; r <= o_hi; r += 16) {
            const float4 v = *reinterpret_cast<const float4*>(
                pb + (size_t)r * LR_TOUT + t0 + 4 * col4);
            if (v.x != 0.0f) owner[4 * col4 + 0] = r;
            if (v.y != 0.0f) owner[4 * col4 + 1] = r;
            if (v.z != 0.0f) owner[4 * col4 + 2] = r;
            if (v.w != 0.0f) owner[4 * col4 + 3] = r;
        }
        __syncthreads();

        if (tid < SCAN_TT / 4) {
            const int4 o = reinterpret_cast<const int4*>(owner)[tid];
            reinterpret_cast<int4*>(idx + b * LR_TOUT + t0)[tid] = o;
        }
    }

    cg::this_grid().sync();

    // ================= phase 2: fat gather-expand =================
    {
        const int c0 = k * CCHUNK;
        const float* xb = x + ((size_t)b * LR_C + c0) * LR_TIN;
#pragma unroll
        for (int j = 0; j < (CCHUNK * LR_TIN) / 512; ++j) {   // 8
            const int l = tid + 512 * j;
            xs[l >> 8][l & 255] = xb[l];
        }
        const int4 iv = *reinterpret_cast<const int4*>(idx + b * LR_TOUT + 4 * tid);
        __syncthreads();

        float* ob = out + ((size_t)b * LR_C + c0) * LR_TOUT + 4 * tid;
#pragma unroll
        for (int ch = 0; ch < CCHUNK; ++ch) {
            float4 o;
            o.x = xs[ch][iv.x];
            o.y = xs[ch][iv.y];
            o.z = xs[ch][iv.z];
            o.w = xs[ch][iv.w];
            *reinterpret_cast<float4*>(ob + (size_t)ch * LR_TOUT) = o;
        }
    }
}

// ---------------- fallback: R10 two-kernel path ----------------

__global__ __launch_bounds__(256) void lr_idx5(const float* __restrict__ path,
                                               int* __restrict__ idx) {
    __shared__ int o_lo_s, o_hi_s;
    __shared__ int owner[SCAN_TT];

    const int tid = threadIdx.x;
    const int t0 = blockIdx.x * SCAN_TT;
    const int b = blockIdx.y;
    const float* pb = path + (size_t)b * LR_TIN * LR_TOUT;

    if (pb[(size_t)tid * LR_TOUT + t0] != 0.0f) o_lo_s = tid;
    if (t0 + SCAN_TT < LR_TOUT) {
        if (pb[(size_t)tid * LR_TOUT + t0 + SCAN_TT] != 0.0f) o_hi_s = tid;
    } else if (tid == 0) {
        o_hi_s = LR_TIN - 1;
    }
    __syncthreads();
    const int o_lo = o_lo_s;
    const int o_hi = o_hi_s;

    const int row_off = tid >> 5;
    const int col4 = tid & 31;
    for (int r = o_lo + row_off; r <= o_hi; r += 8) {
        const float4 v = *reinterpret_cast<const float4*>(
            pb + (size_t)r * LR_TOUT + t0 + 4 * col4);
        if (v.x != 0.0f) owner[4 * col4 + 0] = r;
        if (v.y != 0.0f) owner[4 * col4 + 1] = r;
        if (v.z != 0.0f) owner[4 * col4 + 2] = r;
        if (v.w != 0.0f) owner[4 * col4 + 3] = r;
    }
    __syncthreads();

    if (tid < SCAN_TT / 4) {
        const int4 o = *reinterpret_cast<const int4*>(&owner[4 * tid]);
        *reinterpret_cast<int4*>(idx + b * LR_TOUT + t0 + 4 * tid) = o;
    }
}

__global__ __launch_bounds__(256) void lr_gather5(const float* __restrict__ x,
                                                  const int* __restrict__ idx,
                                                  float* __restrict__ out) {
    __shared__ float xs[8][LR_TIN];

    const int c0 = blockIdx.x * 8;
    const int b = blockIdx.y;
    const int tid = threadIdx.x;

    {
        const float* xb = x + ((size_t)b * LR_C + c0) * LR_TIN;
#pragma unroll
        for (int ch = 0; ch < 8; ++ch) {
            xs[ch][tid] = xb[(size_t)ch * LR_TIN + tid];
        }
    }

    const int* ib = idx + b * LR_TOUT;
    const int t0 = 4 * tid;
    const int4 iv0 = *reinterpret_cast<const int4*>(ib + t0);
    const int4 iv1 = *reinterpret_cast<const int4*>(ib + t0 + LR_TOUT / 2);
    __syncthreads();

    float* ob = out + ((size_t)b * LR_C + c0) * LR_TOUT;
#pragma unroll
    for (int ch = 0; ch < 8; ++ch) {
        float4 o0, o1;
        o0.x = xs[ch][iv0.x]; o0.y = xs[ch][iv0.y];
        o0.z = xs[ch][iv0.z]; o0.w = xs[ch][iv0.w];
        o1.x = xs[ch][iv1.x]; o1.y = xs[ch][iv1.y];
        o1.z = xs[ch][iv1.z]; o1.w = xs[ch][iv1.w];
        float* oc = ob + (size_t)ch * LR_TOUT;
        *reinterpret_cast<float4*>(oc + t0) = o0;
        *reinterpret_cast<float4*>(oc + t0 + LR_TOUT / 2) = o1;
    }
}

extern "C" void kernel_launch(void* const* d_in, const int* in_sizes, int n_in,
                              void* d_out, int out_size, void* d_ws, size_t ws_size,
                              hipStream_t stream) {
    const float* x    = (const float*)d_in[0];   // [B, C, T_IN] fp32
    const float* path = (const float*)d_in[1];   // [B, T_IN, T_OUT] fp32
    float* out = (float*)d_out;                  // [B, C, T_OUT] fp32

    const size_t idx_bytes = (size_t)LR_B * LR_TOUT * sizeof(int);
    if (ws_size >= idx_bytes) {
        int* idx = (int*)d_ws;
        void* args[] = {(void*)&x, (void*)&path, (void*)&idx, (void*)&out};
        hipError_t err = hipLaunchCooperativeKernel(
            (void*)lr_coop, dim3(512), dim3(512), args, 0, stream);
        if (err != hipSuccess) {
            lr_idx5<<<dim3(LR_TOUT / SCAN_TT, LR_B), 256, 0, stream>>>(path, idx);
            lr_gather5<<<dim3(LR_C / 8, LR_B), 256, 0, stream>>>(x, idx, out);
        }
    } else {
        // no workspace: two-pass via out as scratch is impossible; use the
        // banded fused kernel (slower but correct, no ws needed)
        // (reuse lr_idx5's logic inline per 64-t tile)
        // Fallback chain: just run the R10 fused path equivalent.
        // For simplicity: full grid fused banded kernel.
        // [This path is not expected to be taken: ws_size >= 256 KiB in harness.]
        lr_idx5<<<dim3(LR_TOUT / SCAN_TT, LR_B), 256, 0, stream>>>((const float*)d_in[1], (int*)d_ws);
        lr_gather5<<<dim3(LR_C / 8, LR_B), 256, 0, stream>>>((const float*)d_in[0], (const int*)d_ws, (float*)d_out);
    }
}

// Round 12
// 24.477 us; speedup vs baseline: 3.1188x; 3.1188x over previous
//
#include <hip/hip_runtime.h>

// LengthRegulator: out[b,c,t] = x[b,c,owner(b,t)]; owner is the unique token
// whose segment covers frame t (path = 0/1 disjoint segment mask tiling
// [0,T_OUT) -> bmm(x,path) == gather; exact). owner(b,t) monotone in t.
//
// K1 (banded idx build, TT=256, 512 threads): anchor phase issues ALL 512
// scattered lo/hi anchor loads concurrently (tid<256 reads column t0 at row
// tid; tid>=256 reads column t0+256 at row tid-256). 256 blocks = 1/CU ->
// whole-GPU anchor scatter in flight at once (latency amortized across 131K
// outstanding lines). Band scan: owner(t) in [o_lo,o_hi] (~33 rows avg at
// TT=256), 8 rows x 64 float4-cols per pass, coalesced. Race-free
// conditional LDS store (exactly one nonzero per t), no init, no atomics.
//
// K2 (fat gather-expand, unchanged from R10): block per (b, 8-channel chunk);
// 8 x-rows staged in LDS; idx int4s loaded once into registers; per channel
// 8 LDS gathers + 2 contiguous float4 stores (1 KiB per wave-store).

#define LR_B 32
#define LR_C 256
#define LR_TIN 256
#define LR_TOUT 2048

#define SCAN_TT 256                   // t-interval per K1 block
#define CCHUNK 8                      // channels per K2 block

__global__ __launch_bounds__(512) void lr_idx6(const float* __restrict__ path,
                                               int* __restrict__ idx) {
    __shared__ int o_lo_s, o_hi_s;
    __shared__ int owner[SCAN_TT];

    const int tid = threadIdx.x;
    const int t0 = blockIdx.x * SCAN_TT;
    const int b = blockIdx.y;
    const float* pb = path + (size_t)b * LR_TIN * LR_TOUT;

    // ---- anchor scans: both columns issued in parallel across 8 waves ----
    if (tid < LR_TIN) {
        if (pb[(size_t)tid * LR_TOUT + t0] != 0.0f) o_lo_s = tid;
    } else {
        const int r = tid - LR_TIN;
        if (t0 + SCAN_TT < LR_TOUT) {
            if (pb[(size_t)r * LR_TOUT + t0 + SCAN_TT] != 0.0f) o_hi_s = r;
        } else if (r == 0) {
            o_hi_s = LR_TIN - 1;
        }
    }
    __syncthreads();
    const int o_lo = o_lo_s;
    const int o_hi = o_hi_s;

    // ---- band scan: 8 rows x 64 float4-cols per pass ----
    const int col4 = tid & 63;        // float4 column within the 256-t tile
    const int row_off = tid >> 6;     // 0..7
    for (int r = o_lo + row_off; r <= o_hi; r += 8) {
        const float4 v = *reinterpret_cast<const float4*>(
            pb + (size_t)r * LR_TOUT + t0 + 4 * col4);
        if (v.x != 0.0f) owner[4 * col4 + 0] = r;
        if (v.y != 0.0f) owner[4 * col4 + 1] = r;
        if (v.z != 0.0f) owner[4 * col4 + 2] = r;
        if (v.w != 0.0f) owner[4 * col4 + 3] = r;
    }
    __syncthreads();

    if (tid < SCAN_TT / 4) {
        const int4 o = *reinterpret_cast<const int4*>(&owner[4 * tid]);
        *reinterpret_cast<int4*>(idx + b * LR_TOUT + t0 + 4 * tid) = o;
    }
}

__global__ __launch_bounds__(256) void lr_gather5(const float* __restrict__ x,
                                                  const int* __restrict__ idx,
                                                  float* __restrict__ out) {
    __shared__ float xs[CCHUNK][LR_TIN];   // 8 KiB

    const int c0 = blockIdx.x * CCHUNK;
    const int b = blockIdx.y;
    const int tid = threadIdx.x;

    {
        const float* xb = x + ((size_t)b * LR_C + c0) * LR_TIN;
#pragma unroll
        for (int ch = 0; ch < CCHUNK; ++ch) {
            xs[ch][tid] = xb[(size_t)ch * LR_TIN + tid];
        }
    }

    const int* ib = idx + b * LR_TOUT;
    const int t0 = 4 * tid;
    const int4 iv0 = *reinterpret_cast<const int4*>(ib + t0);
    const int4 iv1 = *reinterpret_cast<const int4*>(ib + t0 + LR_TOUT / 2);
    __syncthreads();

    float* ob = out + ((size_t)b * LR_C + c0) * LR_TOUT;
#pragma unroll
    for (int ch = 0; ch < CCHUNK; ++ch) {
        float4 o0, o1;
        o0.x = xs[ch][iv0.x]; o0.y = xs[ch][iv0.y];
        o0.z = xs[ch][iv0.z]; o0.w = xs[ch][iv0.w];
        o1.x = xs[ch][iv1.x]; o1.y = xs[ch][iv1.y];
        o1.z = xs[ch][iv1.z]; o1.w = xs[ch][iv1.w];
        float* oc = ob + (size_t)ch * LR_TOUT;
        *reinterpret_cast<float4*>(oc + t0) = o0;
        *reinterpret_cast<float4*>(oc + t0 + LR_TOUT / 2) = o1;
    }
}

// Fallback (no workspace): banded fused kernel, correct but slower.
__global__ __launch_bounds__(256) void lr_fused5(const float* __restrict__ x,
                                                 const float* __restrict__ path,
                                                 float* __restrict__ out) {
    __shared__ int owner[64];
    __shared__ int o_lo_s, o_hi_s;
    const int tid = threadIdx.x;
    const int t0 = blockIdx.x * 64;
    const int b  = blockIdx.y;
    const float* pb = path + (size_t)b * LR_TIN * LR_TOUT;

    if (pb[(size_t)tid * LR_TOUT + t0] != 0.0f) o_lo_s = tid;
    if (t0 + 64 < LR_TOUT) {
        if (pb[(size_t)tid * LR_TOUT + t0 + 64] != 0.0f) o_hi_s = tid;
    } else if (tid == 0) {
        o_hi_s = LR_TIN - 1;
    }
    __syncthreads();
    const int o_lo = o_lo_s;
    const int o_hi = o_hi_s;

    const int col4 = tid & 15;
    const int row_off = tid >> 4;
    for (int r = o_lo + row_off; r <= o_hi; r += 16) {
        const float4 v = *reinterpret_cast<const float4*>(
            pb + (size_t)r * LR_TOUT + t0 + 4 * col4);
        if (v.x != 0.0f) owner[4 * col4 + 0] = r;
        if (v.y != 0.0f) owner[4 * col4 + 1] = r;
        if (v.z != 0.0f) owner[4 * col4 + 2] = r;
        if (v.w != 0.0f) owner[4 * col4 + 3] = r;
    }
    __syncthreads();

    const int4 iv = *reinterpret_cast<const int4*>(&owner[4 * col4]);
    const int cbase = tid >> 4;
    const float* xb = x + (size_t)b * LR_C * LR_TIN;
    float* ob = out + (size_t)b * LR_C * LR_TOUT + t0 + 4 * col4;
#pragma unroll
    for (int j = 0; j < LR_C / 16; ++j) {
        const int c = cbase + 16 * j;
        const float* xr = xb + (size_t)c * LR_TIN;
        float4 o;
        o.x = xr[iv.x]; o.y = xr[iv.y]; o.z = xr[iv.z]; o.w = xr[iv.w];
        *reinterpret_cast<float4*>(ob + (size_t)c * LR_TOUT) = o;
    }
}

extern "C" void kernel_launch(void* const* d_in, const int* in_sizes, int n_in,
                              void* d_out, int out_size, void* d_ws, size_t ws_size,
                              hipStream_t stream) {
    const float* x    = (const float*)d_in[0];   // [B, C, T_IN] fp32
    const float* path = (const float*)d_in[1];   // [B, T_IN, T_OUT] fp32
    float* out = (float*)d_out;                  // [B, C, T_OUT] fp32

    const size_t idx_bytes = (size_t)LR_B * LR_TOUT * sizeof(int);
    if (ws_size >= idx_bytes) {
        int* idx = (int*)d_ws;
        lr_idx6<<<dim3(LR_TOUT / SCAN_TT, LR_B), 512, 0, stream>>>(path, idx);
        lr_gather5<<<dim3(LR_C / CCHUNK, LR_B), 256, 0, stream>>>(x, idx, out);
    } else {
        lr_fused5<<<dim3(LR_TOUT / 64, LR_B), 256, 0, stream>>>(x, path, out);
    }
}